// Round 1
// baseline (36283.673 us; speedup 1.0000x reference)
//
#include <hip/hip_runtime.h>
#include <hip/hip_cooperative_groups.h>

namespace cg = cooperative_groups;

#define SEQ   512
#define BATCH 64
#define DIM   1024
#define HID   1024
#define GCOLS 4096   // 4 gates * HID

// ---------- bf16 helpers (raw ushort, RNE) ----------
__device__ __forceinline__ unsigned short f2bf(float f) {
  union { float f; unsigned int u; } v; v.f = f;
  unsigned int r = v.u + 0x7FFFu + ((v.u >> 16) & 1u);
  return (unsigned short)(r >> 16);
}
__device__ __forceinline__ float bf2f(unsigned short u) {
  union { unsigned int u; float f; } v; v.u = ((unsigned int)u) << 16;
  return v.f;
}

__device__ __forceinline__ float sigm(float x) {
  return 1.f / (1.f + __expf(-x));
}
// overflow-safe tanh (c can reach large |.|)
__device__ __forceinline__ float tanh_s(float x) {
  float a = fabsf(x);
  float e = __expf(-2.f * a);
  float r = (1.f - e) / (1.f + e);
  return x < 0.f ? -r : r;
}

// ---------- Phase 1: G[(t*64+b)][g*1024+j] = x@Wx_g + bx_g + bh_g (bf16 out) ----------
// grid (8, 256, 4-gates), block 256. 128x128 tile, BK=8, 8x8 microtile, fp32.
__global__ __launch_bounds__(256) void gemm_x(
    const float* __restrict__ X,
    const float* __restrict__ W0, const float* __restrict__ W1,
    const float* __restrict__ W2, const float* __restrict__ W3,
    const float* __restrict__ bx0, const float* __restrict__ bx1,
    const float* __restrict__ bx2, const float* __restrict__ bx3,
    const float* __restrict__ bh0, const float* __restrict__ bh1,
    const float* __restrict__ bh2, const float* __restrict__ bh3,
    unsigned short* __restrict__ G)
{
  __shared__ __align__(16) float As[8][132];   // [k][m], +4 pad
  __shared__ __align__(16) float Bs[8][132];   // [k][n], +4 pad

  const int tid = threadIdx.x;
  const int g   = blockIdx.z;
  const float* W  = (g==0) ? W0  : (g==1) ? W1  : (g==2) ? W2  : W3;
  const float* bx = (g==0) ? bx0 : (g==1) ? bx1 : (g==2) ? bx2 : bx3;
  const float* bh = (g==0) ? bh0 : (g==1) ? bh1 : (g==2) ? bh2 : bh3;
  const int n0 = blockIdx.x * 128;   // j offset within gate
  const int m0 = blockIdx.y * 128;   // row = t*64+b
  const int tx = tid & 15, ty = tid >> 4;

  const int am = tid >> 1;          // 0..127
  const int ak = (tid & 1) * 4;     // 0 or 4
  const int bk = tid >> 5;          // 0..7
  const int bn = (tid & 31) * 4;    // 0..124

  float acc[8][8];
#pragma unroll
  for (int i = 0; i < 8; ++i)
#pragma unroll
    for (int j = 0; j < 8; ++j) acc[i][j] = 0.f;

  for (int k0 = 0; k0 < DIM; k0 += 8) {
    float4 av = *(const float4*)(X + (size_t)(m0 + am) * DIM + k0 + ak);
    float4 bv = *(const float4*)(W + (size_t)(k0 + bk) * HID + n0 + bn);
    __syncthreads();
    As[ak+0][am] = av.x; As[ak+1][am] = av.y; As[ak+2][am] = av.z; As[ak+3][am] = av.w;
    *(float4*)&Bs[bk][bn] = bv;
    __syncthreads();
#pragma unroll
    for (int kk = 0; kk < 8; ++kk) {
      float4 a0 = *(const float4*)&As[kk][ty*8];
      float4 a1 = *(const float4*)&As[kk][ty*8+4];
      float4 b0 = *(const float4*)&Bs[kk][tx*8];
      float4 b1 = *(const float4*)&Bs[kk][tx*8+4];
      float ar[8] = {a0.x,a0.y,a0.z,a0.w,a1.x,a1.y,a1.z,a1.w};
      float br[8] = {b0.x,b0.y,b0.z,b0.w,b1.x,b1.y,b1.z,b1.w};
#pragma unroll
      for (int i = 0; i < 8; ++i)
#pragma unroll
        for (int j = 0; j < 8; ++j)
          acc[i][j] = __builtin_fmaf(ar[i], br[j], acc[i][j]);
    }
  }

  const int gOff = g * HID;
  float bias[8];
#pragma unroll
  for (int j = 0; j < 8; ++j) {
    int c = n0 + tx*8 + j;
    bias[j] = bx[c] + bh[c];
  }
#pragma unroll
  for (int i = 0; i < 8; ++i) {
    size_t base = (size_t)(m0 + ty*8 + i) * GCOLS + gOff + n0 + tx*8;
    ushort4 lo, hi;
    lo.x = f2bf(acc[i][0] + bias[0]); lo.y = f2bf(acc[i][1] + bias[1]);
    lo.z = f2bf(acc[i][2] + bias[2]); lo.w = f2bf(acc[i][3] + bias[3]);
    hi.x = f2bf(acc[i][4] + bias[4]); hi.y = f2bf(acc[i][5] + bias[5]);
    hi.z = f2bf(acc[i][6] + bias[6]); hi.w = f2bf(acc[i][7] + bias[7]);
    *(ushort4*)(G + base)     = lo;   // 8B stores, 16B-aligned pair
    *(ushort4*)(G + base + 4) = hi;
  }
}

// ---------- Phase 2: persistent cooperative recurrence ----------
// 256 blocks x 256 threads. Block bid owns hidden units j0..j0+3 (16 gate cols).
// Wh slice (16 cols x 1024 k, fp32 = 64KB+pad) lives in LDS for all 512 steps.
// Lane (col=lane&15, bq=lane>>4) in wave wv accumulates 4 batches b0..b0+3,
// full K=1024 per lane (no cross-lane reduction). c stays in a register.
__global__ __launch_bounds__(256) void lstm_rec(
    const unsigned short* __restrict__ G,   // [512*64][4096] bf16
    const float* __restrict__ Whf, const float* __restrict__ Whi,
    const float* __restrict__ Who, const float* __restrict__ Whc,
    float* __restrict__ hbuf,               // [2][64][1024] ping-pong
    float* __restrict__ out)                // h_seq | h | c
{
  __shared__ __align__(16) float Wl[16][1028];  // [g*4+u][k], +4 pad
  __shared__ float pre[64][17];                 // preactivations, +1 pad

  const int tid = threadIdx.x;
  const int bid = blockIdx.x;
  const int j0  = bid * 4;

  // load Wh slice into LDS (one time)
  for (int g = 0; g < 4; ++g) {
    const float* W = (g==0) ? Whf : (g==1) ? Whi : (g==2) ? Who : Whc;
    for (int idx = tid; idx < 4 * 1024; idx += 256) {
      int u = idx & 3, k = idx >> 2;
      Wl[g*4 + u][k] = W[(size_t)k * HID + j0 + u];
    }
  }
  // zero h0 slice owned by this block
  {
    int b = tid >> 2, u = tid & 3;
    hbuf[b * HID + j0 + u] = 0.f;
  }

  const int lane = tid & 63;
  const int wv   = tid >> 6;         // wave 0..3
  const int ci   = lane & 15;        // col index: g*4+u
  const int bq   = lane >> 4;        // 0..3
  const int b0   = wv * 16 + bq * 4; // first of this lane's 4 batches
  const int colg = (ci >> 2) * HID + j0 + (ci & 3);  // global gate column

  const int gb = tid >> 2, gu = tid & 3;  // gate-update mapping (fixed across steps)
  float c_reg = 0.f;

  cg::grid_group grid = cg::this_grid();
  grid.sync();   // h0 visible everywhere

  for (int t = 0; t < SEQ; ++t) {
    const float* hc  = hbuf + (t & 1) * (BATCH * HID);
    const float* hp0 = hc + (size_t)(b0 + 0) * HID;
    const float* hp1 = hc + (size_t)(b0 + 1) * HID;
    const float* hp2 = hc + (size_t)(b0 + 2) * HID;
    const float* hp3 = hc + (size_t)(b0 + 3) * HID;
    float acc0 = 0.f, acc1 = 0.f, acc2 = 0.f, acc3 = 0.f;
#pragma unroll 4
    for (int k = 0; k < DIM; k += 4) {
      float4 w4 = *(const float4*)&Wl[ci][k];
      float4 h0 = *(const float4*)(hp0 + k);
      float4 h1 = *(const float4*)(hp1 + k);
      float4 h2 = *(const float4*)(hp2 + k);
      float4 h3 = *(const float4*)(hp3 + k);
      acc0 = __builtin_fmaf(w4.x,h0.x,__builtin_fmaf(w4.y,h0.y,__builtin_fmaf(w4.z,h0.z,__builtin_fmaf(w4.w,h0.w,acc0))));
      acc1 = __builtin_fmaf(w4.x,h1.x,__builtin_fmaf(w4.y,h1.y,__builtin_fmaf(w4.z,h1.z,__builtin_fmaf(w4.w,h1.w,acc1))));
      acc2 = __builtin_fmaf(w4.x,h2.x,__builtin_fmaf(w4.y,h2.y,__builtin_fmaf(w4.z,h2.z,__builtin_fmaf(w4.w,h2.w,acc2))));
      acc3 = __builtin_fmaf(w4.x,h3.x,__builtin_fmaf(w4.y,h3.y,__builtin_fmaf(w4.z,h3.z,__builtin_fmaf(w4.w,h3.w,acc3))));
    }
    const unsigned short* Gt = G + (size_t)t * (BATCH * GCOLS);
    pre[b0+0][ci] = acc0 + bf2f(Gt[(size_t)(b0+0) * GCOLS + colg]);
    pre[b0+1][ci] = acc1 + bf2f(Gt[(size_t)(b0+1) * GCOLS + colg]);
    pre[b0+2][ci] = acc2 + bf2f(Gt[(size_t)(b0+2) * GCOLS + colg]);
    pre[b0+3][ci] = acc3 + bf2f(Gt[(size_t)(b0+3) * GCOLS + colg]);
    __syncthreads();

    {
      float pf = pre[gb][gu];
      float pi = pre[gb][4 + gu];
      float po = pre[gb][8 + gu];
      float pg = pre[gb][12 + gu];
      float f  = sigm(pf);
      float i  = sigm(pi);
      float o  = sigm(po);
      float gg = tanh_s(pg);
      c_reg = f * c_reg + i * gg;
      float h = o * tanh_s(c_reg);
      float* hn = hbuf + ((t + 1) & 1) * (BATCH * HID);
      hn[gb * HID + j0 + gu] = h;
      out[((size_t)t * BATCH + gb) * HID + j0 + gu] = h;
      if (t == SEQ - 1) {
        out[(size_t)SEQ * BATCH * HID + gb * HID + j0 + gu] = h;
        out[(size_t)SEQ * BATCH * HID + BATCH * HID + gb * HID + j0 + gu] = c_reg;
      }
    }
    grid.sync();  // device-scope acq/rel: h_new visible (incl. cross-XCD), pre[] safe to reuse
  }
}

extern "C" void kernel_launch(void* const* d_in, const int* in_sizes, int n_in,
                              void* d_out, int out_size, void* d_ws, size_t ws_size,
                              hipStream_t stream)
{
  // setup_inputs() dict order: x, Wxf,bxf, Wxi,bxi, Wxo,bxo, Wxc,bxc,
  //                            Whf,bhf, Whi,bhi, Who,bho, Whc,bhc
  const float* x   = (const float*)d_in[0];
  const float* Wxf = (const float*)d_in[1];
  const float* bxf = (const float*)d_in[2];
  const float* Wxi = (const float*)d_in[3];
  const float* bxi = (const float*)d_in[4];
  const float* Wxo = (const float*)d_in[5];
  const float* bxo = (const float*)d_in[6];
  const float* Wxc = (const float*)d_in[7];
  const float* bxc = (const float*)d_in[8];
  const float* Whf = (const float*)d_in[9];
  const float* bhf = (const float*)d_in[10];
  const float* Whi = (const float*)d_in[11];
  const float* bhi = (const float*)d_in[12];
  const float* Who = (const float*)d_in[13];
  const float* bho = (const float*)d_in[14];
  const float* Whc = (const float*)d_in[15];
  const float* bhc = (const float*)d_in[16];

  // ws layout: G bf16 [512*64][4096] (256MB), then hbuf fp32 [2][64][1024]
  unsigned short* G = (unsigned short*)d_ws;
  float* hbuf = (float*)((char*)d_ws + (size_t)SEQ * BATCH * GCOLS * sizeof(unsigned short));
  float* out  = (float*)d_out;

  dim3 g1(8, 256, 4);
  hipLaunchKernelGGL(gemm_x, g1, dim3(256), 0, stream,
                     x, Wxf, Wxi, Wxo, Wxc,
                     bxf, bxi, bxo, bxc,
                     bhf, bhi, bho, bhc, G);

  void* args[] = { (void*)&G, (void*)&Whf, (void*)&Whi, (void*)&Who, (void*)&Whc,
                   (void*)&hbuf, (void*)&out };
  hipLaunchCooperativeKernel((void*)lstm_rec, dim3(256), dim3(256), args, 0, stream);
}

// Round 2
// 22121.198 us; speedup vs baseline: 1.6402x; 1.6402x over previous
//
#include <hip/hip_runtime.h>
#include <hip/hip_cooperative_groups.h>

namespace cg = cooperative_groups;

#define SEQ   512
#define BATCH 64
#define DIM   1024
#define HID   1024
#define GCOLS 4096   // 4 gates * HID (column-permuted: col' = bid*16 + g*4 + u)

typedef float  floatx4 __attribute__((ext_vector_type(4)));
typedef short  shortx8 __attribute__((ext_vector_type(8)));
union ABFrag { uint4 u; shortx8 s; };

// ---------- bf16 helpers (raw ushort, RNE) ----------
__device__ __forceinline__ unsigned short f2bf(float f) {
  union { float f; unsigned int u; } v; v.f = f;
  unsigned int r = v.u + 0x7FFFu + ((v.u >> 16) & 1u);
  return (unsigned short)(r >> 16);
}
__device__ __forceinline__ float bf2f(unsigned short u) {
  union { unsigned int u; float f; } v; v.u = ((unsigned int)u) << 16;
  return v.f;
}

__device__ __forceinline__ float sigm(float x) {
  return 1.f / (1.f + __expf(-x));
}
__device__ __forceinline__ float tanh_s(float x) {
  float a = fabsf(x);
  float e = __expf(-2.f * a);
  float r = (1.f - e) / (1.f + e);
  return x < 0.f ? -r : r;
}

// ---------- Phase 1: G[(t*64+b)][(c>>2)*16 + g*4 + (c&3)] = x@Wx_g + bx_g + bh_g (bf16) ----------
// grid (8, 256, 4-gates), block 256. 128x128 tile, BK=8, 8x8 microtile, fp32 VALU.
__global__ __launch_bounds__(256) void gemm_x(
    const float* __restrict__ X,
    const float* __restrict__ W0, const float* __restrict__ W1,
    const float* __restrict__ W2, const float* __restrict__ W3,
    const float* __restrict__ bx0, const float* __restrict__ bx1,
    const float* __restrict__ bx2, const float* __restrict__ bx3,
    const float* __restrict__ bh0, const float* __restrict__ bh1,
    const float* __restrict__ bh2, const float* __restrict__ bh3,
    unsigned short* __restrict__ G)
{
  __shared__ __align__(16) float As[8][132];   // [k][m], +4 pad
  __shared__ __align__(16) float Bs[8][132];   // [k][n], +4 pad

  const int tid = threadIdx.x;
  const int g   = blockIdx.z;
  const float* W  = (g==0) ? W0  : (g==1) ? W1  : (g==2) ? W2  : W3;
  const float* bx = (g==0) ? bx0 : (g==1) ? bx1 : (g==2) ? bx2 : bx3;
  const float* bh = (g==0) ? bh0 : (g==1) ? bh1 : (g==2) ? bh2 : bh3;
  const int n0 = blockIdx.x * 128;   // col offset within gate
  const int m0 = blockIdx.y * 128;   // row = t*64+b
  const int tx = tid & 15, ty = tid >> 4;

  const int am = tid >> 1;          // 0..127
  const int ak = (tid & 1) * 4;     // 0 or 4
  const int bk = tid >> 5;          // 0..7
  const int bn = (tid & 31) * 4;    // 0..124

  float acc[8][8];
#pragma unroll
  for (int i = 0; i < 8; ++i)
#pragma unroll
    for (int j = 0; j < 8; ++j) acc[i][j] = 0.f;

  for (int k0 = 0; k0 < DIM; k0 += 8) {
    float4 av = *(const float4*)(X + (size_t)(m0 + am) * DIM + k0 + ak);
    float4 bv = *(const float4*)(W + (size_t)(k0 + bk) * HID + n0 + bn);
    __syncthreads();
    As[ak+0][am] = av.x; As[ak+1][am] = av.y; As[ak+2][am] = av.z; As[ak+3][am] = av.w;
    *(float4*)&Bs[bk][bn] = bv;
    __syncthreads();
#pragma unroll
    for (int kk = 0; kk < 8; ++kk) {
      float4 a0 = *(const float4*)&As[kk][ty*8];
      float4 a1 = *(const float4*)&As[kk][ty*8+4];
      float4 b0 = *(const float4*)&Bs[kk][tx*8];
      float4 b1 = *(const float4*)&Bs[kk][tx*8+4];
      float ar[8] = {a0.x,a0.y,a0.z,a0.w,a1.x,a1.y,a1.z,a1.w};
      float br[8] = {b0.x,b0.y,b0.z,b0.w,b1.x,b1.y,b1.z,b1.w};
#pragma unroll
      for (int i = 0; i < 8; ++i)
#pragma unroll
        for (int j = 0; j < 8; ++j)
          acc[i][j] = __builtin_fmaf(ar[i], br[j], acc[i][j]);
    }
  }

  const int c0 = n0 + tx*8;
  float bias[8];
#pragma unroll
  for (int j = 0; j < 8; ++j) bias[j] = bx[c0 + j] + bh[c0 + j];

  // permuted store: col c -> (c>>2)*16 + g*4 + (c&3). c0 multiple of 8:
  // j=0..3 -> (c0>>2)*16 + g*4 + j ; j=4..7 -> +16.
  const size_t cbase = (size_t)(c0 >> 2) * 16 + g * 4;
#pragma unroll
  for (int i = 0; i < 8; ++i) {
    size_t rowbase = (size_t)(m0 + ty*8 + i) * GCOLS;
    ushort4 lo, hi;
    lo.x = f2bf(acc[i][0] + bias[0]); lo.y = f2bf(acc[i][1] + bias[1]);
    lo.z = f2bf(acc[i][2] + bias[2]); lo.w = f2bf(acc[i][3] + bias[3]);
    hi.x = f2bf(acc[i][4] + bias[4]); hi.y = f2bf(acc[i][5] + bias[5]);
    hi.z = f2bf(acc[i][6] + bias[6]); hi.w = f2bf(acc[i][7] + bias[7]);
    *(ushort4*)(G + rowbase + cbase)      = lo;   // 8B each, same 64B line
    *(ushort4*)(G + rowbase + cbase + 16) = hi;
  }
}

// ---------- Phase 2: persistent cooperative recurrence, MFMA ----------
// 256 blocks x 256 threads (4 waves). Block bid owns hidden units j0..j0+3
// (16 gate cols). Wh slice pre-swizzled to bf16 B-fragments in LDS (32KB,
// loaded once). Wave wv computes C-tile [16 batches x 16 cols] via
// 32 x mfma_f32_16x16x32_bf16 per step. A-fragments load straight from the
// bf16 h ping-pong buffer (one dwordx4/lane/ktile; A layout m=lane&15,
// k=(lane>>4)*8+j makes the fragment 16B contiguous).
__global__ __launch_bounds__(256) void lstm_rec(
    const unsigned short* __restrict__ G,   // [512*64][4096] bf16, col-permuted
    const float* __restrict__ Whf, const float* __restrict__ Whi,
    const float* __restrict__ Who, const float* __restrict__ Whc,
    unsigned short* __restrict__ hbuf,      // bf16 [2][64][1024] ping-pong
    float* __restrict__ out)                // h_seq | h | c (fp32)
{
  __shared__ __align__(16) unsigned short Wswz[32 * 64 * 8]; // 32KB B-fragments
  __shared__ float pre[64][17];                              // preacts, +1 pad
  __shared__ __align__(8) unsigned short GshA[64][4][4];     // [b][g][u]

  const int tid  = threadIdx.x;
  const int bid  = blockIdx.x;
  const int j0   = bid * 4;
  const int lane = tid & 63;
  const int wv   = tid >> 6;

  // One-time: swizzle Wh columns into MFMA B-fragment order.
  // B[k][n]: n = lane&15, k = (lane>>4)*8 + j (j contiguous in the fragment).
  for (int idx = tid; idx < 32 * 64; idx += 256) {
    int kt = idx >> 6, l = idx & 63;
    int ci = l & 15, g = ci >> 2, u = ci & 3;
    const float* W = (g==0) ? Whf : (g==1) ? Whi : (g==2) ? Who : Whc;
    int kbase = kt * 32 + (l >> 4) * 8;
    unsigned short* dst = &Wswz[idx * 8];
#pragma unroll
    for (int j = 0; j < 8; ++j)
      dst[j] = f2bf(W[(size_t)(kbase + j) * HID + j0 + u]);
  }
  // zero h0 slice owned by this block (bf16)
  { int b = tid >> 2, u = tid & 3; hbuf[b * HID + j0 + u] = 0; }

  const int ar = lane & 15;      // A row in tile / C col
  const int aq = lane >> 4;      // quad
  const int mrow = wv * 16 + ar; // batch row this lane loads for A
  const int gb = tid >> 2, gu = tid & 3;      // pointwise mapping (fixed)
  const int gB = tid & 63, gG = tid >> 6;     // G prefetch mapping
  float c_reg = 0.f;

  cg::grid_group grid = cg::this_grid();
  grid.sync();   // Wswz + h0 ready everywhere

  for (int t = 0; t < SEQ; ++t) {
    const unsigned short* hp = hbuf + (t & 1) * (BATCH * HID);
    const unsigned short* Gt = G + (size_t)t * (BATCH * GCOLS);

    // prefetch this block's 2KB G slice (ushort4 per (b,g)), hidden under MFMA
    ushort4 gv = *(const ushort4*)(Gt + (size_t)gB * GCOLS + bid * 16 + gG * 4);

    floatx4 acc = {0.f, 0.f, 0.f, 0.f};
    const unsigned short* arow = hp + (size_t)mrow * HID + aq * 8;
#pragma unroll 8
    for (int kt = 0; kt < 32; ++kt) {
      ABFrag a, b;
      a.u = *(const uint4*)(arow + kt * 32);
      b.u = *(const uint4*)&Wswz[kt * 512 + lane * 8];
      acc = __builtin_amdgcn_mfma_f32_16x16x32_bf16(a.s, b.s, acc, 0, 0, 0);
    }

    *(ushort4*)&GshA[gB][gG][0] = gv;
    // C layout: col = lane&15, row = (lane>>4)*4 + reg
#pragma unroll
    for (int r = 0; r < 4; ++r)
      pre[wv * 16 + aq * 4 + r][ar] = acc[r];
    __syncthreads();

    {
      float pf = pre[gb][gu]      + bf2f(GshA[gb][0][gu]);
      float pi = pre[gb][4 + gu]  + bf2f(GshA[gb][1][gu]);
      float po = pre[gb][8 + gu]  + bf2f(GshA[gb][2][gu]);
      float pg = pre[gb][12 + gu] + bf2f(GshA[gb][3][gu]);
      float f  = sigm(pf);
      float i  = sigm(pi);
      float o  = sigm(po);
      float gg = tanh_s(pg);
      c_reg = f * c_reg + i * gg;
      float h = o * tanh_s(c_reg);
      unsigned short* hn = hbuf + ((t + 1) & 1) * (BATCH * HID);
      hn[gb * HID + j0 + gu] = f2bf(h);
      out[((size_t)t * BATCH + gb) * HID + j0 + gu] = h;
      if (t == SEQ - 1) {
        out[(size_t)SEQ * BATCH * HID + gb * HID + j0 + gu] = h;
        out[(size_t)SEQ * BATCH * HID + BATCH * HID + gb * HID + j0 + gu] = c_reg;
      }
    }
    grid.sync();  // h_new + pre reuse safe (device-scope fence)
  }
}

extern "C" void kernel_launch(void* const* d_in, const int* in_sizes, int n_in,
                              void* d_out, int out_size, void* d_ws, size_t ws_size,
                              hipStream_t stream)
{
  const float* x   = (const float*)d_in[0];
  const float* Wxf = (const float*)d_in[1];
  const float* bxf = (const float*)d_in[2];
  const float* Wxi = (const float*)d_in[3];
  const float* bxi = (const float*)d_in[4];
  const float* Wxo = (const float*)d_in[5];
  const float* bxo = (const float*)d_in[6];
  const float* Wxc = (const float*)d_in[7];
  const float* bxc = (const float*)d_in[8];
  const float* Whf = (const float*)d_in[9];
  const float* bhf = (const float*)d_in[10];
  const float* Whi = (const float*)d_in[11];
  const float* bhi = (const float*)d_in[12];
  const float* Who = (const float*)d_in[13];
  const float* bho = (const float*)d_in[14];
  const float* Whc = (const float*)d_in[15];
  const float* bhc = (const float*)d_in[16];

  // ws layout: G bf16 [512*64][4096] (256MB), then hbuf bf16 [2][64][1024]
  unsigned short* G    = (unsigned short*)d_ws;
  unsigned short* hbuf = (unsigned short*)((char*)d_ws
                        + (size_t)SEQ * BATCH * GCOLS * sizeof(unsigned short));
  float* out = (float*)d_out;

  dim3 g1(8, 256, 4);
  hipLaunchKernelGGL(gemm_x, g1, dim3(256), 0, stream,
                     x, Wxf, Wxi, Wxo, Wxc,
                     bxf, bxi, bxo, bxc,
                     bhf, bhi, bho, bhc, G);

  void* args[] = { (void*)&G, (void*)&Whf, (void*)&Whi, (void*)&Who, (void*)&Whc,
                   (void*)&hbuf, (void*)&out };
  hipLaunchCooperativeKernel((void*)lstm_rec, dim3(256), dim3(256), args, 0, stream);
}

// Round 4
// 10720.638 us; speedup vs baseline: 3.3845x; 2.0634x over previous
//
#include <hip/hip_runtime.h>
#include <hip/hip_cooperative_groups.h>

namespace cg = cooperative_groups;

#define SEQ   512
#define BATCH 64
#define DIM   1024
#define HID   1024
#define GCOLS 4096   // 4 gates * HID (column-permuted: col' = (c>>2)*16 + g*4 + (c&3))

typedef float  floatx4 __attribute__((ext_vector_type(4)));
typedef short  shortx8 __attribute__((ext_vector_type(8)));
union ABFrag  { uint4 u; shortx8 s; };
union ABFrag2 { unsigned long long q[2]; uint4 u; shortx8 s; };

// ---------- bf16 helpers (raw ushort, RNE) ----------
__device__ __forceinline__ unsigned short f2bf(float f) {
  union { float f; unsigned int u; } v; v.f = f;
  unsigned int r = v.u + 0x7FFFu + ((v.u >> 16) & 1u);
  return (unsigned short)(r >> 16);
}
__device__ __forceinline__ float bf2f(unsigned short u) {
  union { unsigned int u; float f; } v; v.u = ((unsigned int)u) << 16;
  return v.f;
}

__device__ __forceinline__ float sigm(float x) {
  return 1.f / (1.f + __expf(-x));
}
__device__ __forceinline__ float tanh_s(float x) {
  float a = fabsf(x);
  float e = __expf(-2.f * a);
  float r = (1.f - e) / (1.f + e);
  return x < 0.f ? -r : r;
}

// ---------- Phase 1: G[(t*64+b)][(c>>2)*16 + g*4 + (c&3)] = x@Wx_g + bx_g + bh_g (bf16) ----------
// (verbatim round 2 — proven)
__global__ __launch_bounds__(256) void gemm_x(
    const float* __restrict__ X,
    const float* __restrict__ W0, const float* __restrict__ W1,
    const float* __restrict__ W2, const float* __restrict__ W3,
    const float* __restrict__ bx0, const float* __restrict__ bx1,
    const float* __restrict__ bx2, const float* __restrict__ bx3,
    const float* __restrict__ bh0, const float* __restrict__ bh1,
    const float* __restrict__ bh2, const float* __restrict__ bh3,
    unsigned short* __restrict__ G)
{
  __shared__ __align__(16) float As[8][132];
  __shared__ __align__(16) float Bs[8][132];

  const int tid = threadIdx.x;
  const int g   = blockIdx.z;
  const float* W  = (g==0) ? W0  : (g==1) ? W1  : (g==2) ? W2  : W3;
  const float* bx = (g==0) ? bx0 : (g==1) ? bx1 : (g==2) ? bx2 : bx3;
  const float* bh = (g==0) ? bh0 : (g==1) ? bh1 : (g==2) ? bh2 : bh3;
  const int n0 = blockIdx.x * 128;
  const int m0 = blockIdx.y * 128;
  const int tx = tid & 15, ty = tid >> 4;

  const int am = tid >> 1;
  const int ak = (tid & 1) * 4;
  const int bk = tid >> 5;
  const int bn = (tid & 31) * 4;

  float acc[8][8];
#pragma unroll
  for (int i = 0; i < 8; ++i)
#pragma unroll
    for (int j = 0; j < 8; ++j) acc[i][j] = 0.f;

  for (int k0 = 0; k0 < DIM; k0 += 8) {
    float4 av = *(const float4*)(X + (size_t)(m0 + am) * DIM + k0 + ak);
    float4 bv = *(const float4*)(W + (size_t)(k0 + bk) * HID + n0 + bn);
    __syncthreads();
    As[ak+0][am] = av.x; As[ak+1][am] = av.y; As[ak+2][am] = av.z; As[ak+3][am] = av.w;
    *(float4*)&Bs[bk][bn] = bv;
    __syncthreads();
#pragma unroll
    for (int kk = 0; kk < 8; ++kk) {
      float4 a0 = *(const float4*)&As[kk][ty*8];
      float4 a1 = *(const float4*)&As[kk][ty*8+4];
      float4 b0 = *(const float4*)&Bs[kk][tx*8];
      float4 b1 = *(const float4*)&Bs[kk][tx*8+4];
      float ar[8] = {a0.x,a0.y,a0.z,a0.w,a1.x,a1.y,a1.z,a1.w};
      float br[8] = {b0.x,b0.y,b0.z,b0.w,b1.x,b1.y,b1.z,b1.w};
#pragma unroll
      for (int i = 0; i < 8; ++i)
#pragma unroll
        for (int j = 0; j < 8; ++j)
          acc[i][j] = __builtin_fmaf(ar[i], br[j], acc[i][j]);
    }
  }

  const int c0 = n0 + tx*8;
  float bias[8];
#pragma unroll
  for (int j = 0; j < 8; ++j) bias[j] = bx[c0 + j] + bh[c0 + j];

  const size_t cbase = (size_t)(c0 >> 2) * 16 + g * 4;
#pragma unroll
  for (int i = 0; i < 8; ++i) {
    size_t rowbase = (size_t)(m0 + ty*8 + i) * GCOLS;
    ushort4 lo, hi;
    lo.x = f2bf(acc[i][0] + bias[0]); lo.y = f2bf(acc[i][1] + bias[1]);
    lo.z = f2bf(acc[i][2] + bias[2]); lo.w = f2bf(acc[i][3] + bias[3]);
    hi.x = f2bf(acc[i][4] + bias[4]); hi.y = f2bf(acc[i][5] + bias[5]);
    hi.z = f2bf(acc[i][6] + bias[6]); hi.w = f2bf(acc[i][7] + bias[7]);
    *(ushort4*)(G + rowbase + cbase)      = lo;
    *(ushort4*)(G + rowbase + cbase + 16) = hi;
  }
}

// ---------- Phase 2: round-2 structure, custom flush-free barrier ----------
// 256 blocks x 256 threads (4 waves), block bid owns hidden units j0=4*bid..+3
// (16 gate cols). Wh B-fragments in LDS (32KB, loaded once). Wave wv computes
// C-tile [16 batches x 16 cols] via 32 x mfma_f32_16x16x32_bf16.
// ALL cross-block h traffic uses relaxed AGENT-scope atomics (coherence-point
// path, no L2 flush needed); per-step sync is a monotonic fetch_add barrier.
__global__ __launch_bounds__(256) void lstm_rec(
    const unsigned short* __restrict__ G,       // [512*64][4096] bf16, permuted
    const float* __restrict__ Whf, const float* __restrict__ Whi,
    const float* __restrict__ Who, const float* __restrict__ Whc,
    unsigned short* __restrict__ hbuf,          // bf16 [2][64][1024] ping-pong
    unsigned long long* __restrict__ barCnt,    // 1 counter
    float* __restrict__ out)                    // h_seq | h | c (fp32)
{
  __shared__ __align__(16) unsigned short Wswz[32 * 64 * 8]; // 32KB B-fragments
  __shared__ float pre[64][17];                              // preacts, +1 pad
  __shared__ __align__(8) unsigned short GshA[64][4][4];     // [b][g][u]
  __shared__ __align__(8) unsigned short hout[64][4];        // [b][u] bf16

  const int tid  = threadIdx.x;
  const int bid  = blockIdx.x;
  const int j0   = bid * 4;
  const int lane = tid & 63;
  const int wv   = tid >> 6;

  // One-time: swizzle Wh columns into MFMA B-fragment order (round-2 verbatim).
  for (int idx = tid; idx < 32 * 64; idx += 256) {
    int kt = idx >> 6, l = idx & 63;
    int ci = l & 15, g = ci >> 2, u = ci & 3;
    const float* W = (g==0) ? Whf : (g==1) ? Whi : (g==2) ? Who : Whc;
    int kbase = kt * 32 + (l >> 4) * 8;
    unsigned short* dst = &Wswz[idx * 8];
#pragma unroll
    for (int j = 0; j < 8; ++j)
      dst[j] = f2bf(W[(size_t)(kbase + j) * HID + j0 + u]);
  }
  // One-time: zero h0 slice (slot 0) via coherent u64 stores
  if (tid < 64) {
    unsigned long long* dst =
        (unsigned long long*)(hbuf + (size_t)tid * HID + j0);
    __hip_atomic_store(dst, 0ull, __ATOMIC_RELAXED, __HIP_MEMORY_SCOPE_AGENT);
  }
  if (bid == 0 && tid == 0)
    __hip_atomic_store(barCnt, 0ull, __ATOMIC_RELAXED, __HIP_MEMORY_SCOPE_AGENT);

  cg::grid_group grid = cg::this_grid();
  grid.sync();   // ONLY init sync: Wswz is block-local; h0 + counter global

  const int ar = lane & 15;      // A row in tile / C col
  const int aq = lane >> 4;      // quad
  const int mrow = wv * 16 + ar; // batch row this lane loads for A
  const int gb = tid >> 2, gu = tid & 3;      // pointwise mapping (fixed)
  const int gB = tid & 63, gG = tid >> 6;     // G prefetch mapping
  float c_reg = 0.f;
  unsigned long long tgt = 0;

  for (int t = 0; t < SEQ; ++t) {
    const unsigned short* hp = hbuf + (t & 1) * (BATCH * HID);
    const unsigned short* Gt = G + (size_t)t * (BATCH * GCOLS);

    // prefetch this block's 2KB G slice (hidden under MFMA)
    ushort4 gv = *(const ushort4*)(Gt + (size_t)gB * GCOLS + bid * 16 + gG * 4);

    // A-fragments straight from coherent h buffer: 2 x u64 atomic loads / ktile
    const unsigned long long* ap =
        (const unsigned long long*)(hp + (size_t)mrow * HID);
    floatx4 acc0 = {0.f, 0.f, 0.f, 0.f};
    floatx4 acc1 = {0.f, 0.f, 0.f, 0.f};
#pragma unroll 8
    for (int kt = 0; kt < 32; kt += 2) {
      ABFrag2 a0, a1; ABFrag b0, b1;
      a0.q[0] = __hip_atomic_load(ap + 8*kt + 2*aq,      __ATOMIC_RELAXED, __HIP_MEMORY_SCOPE_AGENT);
      a0.q[1] = __hip_atomic_load(ap + 8*kt + 2*aq + 1,  __ATOMIC_RELAXED, __HIP_MEMORY_SCOPE_AGENT);
      a1.q[0] = __hip_atomic_load(ap + 8*kt + 8 + 2*aq,  __ATOMIC_RELAXED, __HIP_MEMORY_SCOPE_AGENT);
      a1.q[1] = __hip_atomic_load(ap + 8*kt + 9 + 2*aq,  __ATOMIC_RELAXED, __HIP_MEMORY_SCOPE_AGENT);
      b0.u = *(const uint4*)&Wswz[kt * 512 + lane * 8];
      b1.u = *(const uint4*)&Wswz[(kt + 1) * 512 + lane * 8];
      acc0 = __builtin_amdgcn_mfma_f32_16x16x32_bf16(a0.s, b0.s, acc0, 0, 0, 0);
      acc1 = __builtin_amdgcn_mfma_f32_16x16x32_bf16(a1.s, b1.s, acc1, 0, 0, 0);
    }

    *(ushort4*)&GshA[gB][gG][0] = gv;
    // C layout: col = lane&15, row = (lane>>4)*4 + reg
#pragma unroll
    for (int r = 0; r < 4; ++r)
      pre[wv * 16 + aq * 4 + r][ar] = acc0[r] + acc1[r];
    __syncthreads();

    // pointwise: thread (gb, gu) = (batch, unit-local)
    {
      float pf = pre[gb][gu]      + bf2f(GshA[gb][0][gu]);
      float pi = pre[gb][4 + gu]  + bf2f(GshA[gb][1][gu]);
      float po = pre[gb][8 + gu]  + bf2f(GshA[gb][2][gu]);
      float pg = pre[gb][12 + gu] + bf2f(GshA[gb][3][gu]);
      float f  = sigm(pf);
      float i  = sigm(pi);
      float o  = sigm(po);
      float gg = tanh_s(pg);
      c_reg = f * c_reg + i * gg;
      float h = o * tanh_s(c_reg);
      hout[gb][gu] = f2bf(h);
      out[((size_t)t * BATCH + gb) * HID + j0 + gu] = h;
      if (t == SEQ - 1) {
        out[(size_t)SEQ * BATCH * HID + gb * HID + j0 + gu] = h;
        out[(size_t)SEQ * BATCH * HID + BATCH * HID + gb * HID + j0 + gu] = c_reg;
      }
    }
    __syncthreads();

    // publish h_new: wave 0, one u64 coherent store per batch row
    if (tid < 64) {
      unsigned long long pv = *(const unsigned long long*)&hout[tid][0];
      unsigned long long* dst = (unsigned long long*)
          (hbuf + ((t + 1) & 1) * (BATCH * HID) + (size_t)tid * HID + j0);
      __hip_atomic_store(dst, pv, __ATOMIC_RELAXED, __HIP_MEMORY_SCOPE_AGENT);
    }
    // flush-free barrier: drain wave-0 stores to coherence point, arrive, spin
    tgt += 256;
    if (tid == 0) {
      asm volatile("s_waitcnt vmcnt(0)" ::: "memory");
      __hip_atomic_fetch_add(barCnt, 1ull, __ATOMIC_RELAXED, __HIP_MEMORY_SCOPE_AGENT);
      while (__hip_atomic_load(barCnt, __ATOMIC_RELAXED, __HIP_MEMORY_SCOPE_AGENT)
             < tgt)
        __builtin_amdgcn_s_sleep(1);
    }
    __syncthreads();  // releases block; next step's A-loads read L3-fresh h
  }
}

extern "C" void kernel_launch(void* const* d_in, const int* in_sizes, int n_in,
                              void* d_out, int out_size, void* d_ws, size_t ws_size,
                              hipStream_t stream)
{
  const float* x   = (const float*)d_in[0];
  const float* Wxf = (const float*)d_in[1];
  const float* bxf = (const float*)d_in[2];
  const float* Wxi = (const float*)d_in[3];
  const float* bxi = (const float*)d_in[4];
  const float* Wxo = (const float*)d_in[5];
  const float* bxo = (const float*)d_in[6];
  const float* Wxc = (const float*)d_in[7];
  const float* bxc = (const float*)d_in[8];
  const float* Whf = (const float*)d_in[9];
  const float* bhf = (const float*)d_in[10];
  const float* Whi = (const float*)d_in[11];
  const float* bhi = (const float*)d_in[12];
  const float* Who = (const float*)d_in[13];
  const float* bho = (const float*)d_in[14];
  const float* Whc = (const float*)d_in[15];
  const float* bhc = (const float*)d_in[16];

  // ws: G bf16 (256MB) | hbuf bf16 [2][64][1024] (256KB) | barrier counter
  const size_t G_BYTES = (size_t)SEQ * BATCH * GCOLS * sizeof(unsigned short);
  const size_t H_BYTES = (size_t)2 * BATCH * HID * sizeof(unsigned short);
  unsigned short* G    = (unsigned short*)d_ws;
  unsigned short* hbuf = (unsigned short*)((char*)d_ws + G_BYTES);
  unsigned long long* barCnt = (unsigned long long*)((char*)d_ws + G_BYTES + H_BYTES);
  float* out = (float*)d_out;

  dim3 g1(8, 256, 4);
  hipLaunchKernelGGL(gemm_x, g1, dim3(256), 0, stream,
                     x, Wxf, Wxi, Wxo, Wxc,
                     bxf, bxi, bxo, bxc,
                     bhf, bhi, bho, bhc, G);

  void* args[] = { (void*)&G, (void*)&Whf, (void*)&Whi, (void*)&Who, (void*)&Whc,
                   (void*)&hbuf, (void*)&barCnt, (void*)&out };
  hipLaunchCooperativeKernel((void*)lstm_rec, dim3(256), dim3(256), args, 0, stream);
}